// Round 9
// baseline (166.921 us; speedup 1.0000x reference)
//
#include <hip/hip_runtime.h>
#include <hip/hip_fp16.h>

#define B_   2
#define T_   256
#define P_   12
#define C_   512
#define H_   8
#define HKV_ 2
#define D_   64
#define S_   (T_ * P_)   // 3072
#define M_   (B_ * S_)   // 6144
#define NQKV 768         // 512 q + 128 k + 128 v

typedef _Float16 half8_t __attribute__((ext_vector_type(8)));
typedef _Float16 half4_t __attribute__((ext_vector_type(4)));
typedef _Float16 half2_t __attribute__((ext_vector_type(2)));
typedef float    float4_t __attribute__((ext_vector_type(4)));

#if __has_builtin(__builtin_amdgcn_exp2f)
#define EXP2(x) __builtin_amdgcn_exp2f(x)
#else
#define EXP2(x) __expf((x) * 0.69314718f)
#endif

#define SOFT_SHIFT 20.0f
#define SOFT_CLAMP2 15.5f
#define QSCALE (0.125f * 1.44269504f)

// direct global -> LDS, 16B per lane; LDS dest = wave-uniform base + lane*16
#define GLDS16(gp, lp)                                                          \
    __builtin_amdgcn_global_load_lds(                                           \
        (const __attribute__((address_space(1))) void*)(gp),                    \
        (__attribute__((address_space(3))) void*)(lp), 16, 0, 0)

__device__ __forceinline__ half8_t cvt8(float4_t u0, float4_t u1) {
    half8_t h;
    h[0] = (_Float16)u0[0]; h[1] = (_Float16)u0[1];
    h[2] = (_Float16)u0[2]; h[3] = (_Float16)u0[3];
    h[4] = (_Float16)u1[0]; h[5] = (_Float16)u1[1];
    h[6] = (_Float16)u1[2]; h[7] = (_Float16)u1[3];
    return h;
}

// ---------------------------------------------------------------------------
// Kernel 0: prep — weights only (hs cast eliminated; qkv reads hs f32).
// ---------------------------------------------------------------------------
__global__ __launch_bounds__(256) void prep_kernel(
    const float* __restrict__ Wq, const float* __restrict__ Wk,
    const float* __restrict__ Wv, const float* __restrict__ Wo,
    _Float16* __restrict__ wcatT,     // [768][512]
    _Float16* __restrict__ woT)       // [512][512]
{
    const int blk = blockIdx.x;
    const int tid = threadIdx.x;

    __shared__ __attribute__((aligned(16))) _Float16 Ts[64][72];
    if (blk < 96) {
        int nt = blk / 8, kt = blk % 8;
        int n0 = nt * 64, k0 = kt * 64;
        const float* src; int srcN, col0;
        if (n0 < 512)      { src = Wq; srcN = 512; col0 = n0; }
        else if (n0 < 640) { src = Wk; srcN = 128; col0 = n0 - 512; }
        else               { src = Wv; srcN = 128; col0 = n0 - 640; }
#pragma unroll
        for (int i = 0; i < 4; ++i) {
            int row = i * 16 + (tid >> 4);
            int cg  = tid & 15;
            float4_t v = *(const float4_t*)(src + (size_t)(k0 + row) * srcN + col0 + cg * 4);
            Ts[cg * 4 + 0][row] = (_Float16)v[0];
            Ts[cg * 4 + 1][row] = (_Float16)v[1];
            Ts[cg * 4 + 2][row] = (_Float16)v[2];
            Ts[cg * 4 + 3][row] = (_Float16)v[3];
        }
        __syncthreads();
#pragma unroll
        for (int i = 0; i < 2; ++i) {
            int seg = i * 256 + tid;
            int row = seg >> 3, s = seg & 7;
            *(half8_t*)(wcatT + (size_t)(n0 + row) * 512 + k0 + s * 8) =
                *(const half8_t*)&Ts[row][s * 8];
        }
    } else {
        int t = blk - 96;
        int nt = t / 8, kt = t % 8;
        int n0 = nt * 64, k0 = kt * 64;
#pragma unroll
        for (int i = 0; i < 4; ++i) {
            int row = i * 16 + (tid >> 4);
            int cg  = tid & 15;
            float4_t v = *(const float4_t*)(Wo + (size_t)(k0 + row) * 512 + n0 + cg * 4);
            Ts[cg * 4 + 0][row] = (_Float16)v[0];
            Ts[cg * 4 + 1][row] = (_Float16)v[1];
            Ts[cg * 4 + 2][row] = (_Float16)v[2];
            Ts[cg * 4 + 3][row] = (_Float16)v[3];
        }
        __syncthreads();
#pragma unroll
        for (int i = 0; i < 2; ++i) {
            int seg = i * 256 + tid;
            int row = seg >> 3, s = seg & 7;
            *(half8_t*)(woT + (size_t)(n0 + row) * 512 + k0 + s * 8) =
                *(const half8_t*)&Ts[row][s * 8];
        }
    }
}

// ---------------------------------------------------------------------------
// Kernel 1: fused QKV GEMM. hs(f32) @ WcatT^T -> q/k/v.
// 64x64 tile, 128 threads (2 waves), wave computes 32x64 (acc[2][4]):
// 16 MFMA per k-step per wave vs 12 LDS reads + 4 writes (ratio 1.0 vs
// R8's 0.67). Grid unchanged (1152 blocks), LDS unchanged (32KB, 5/CU).
// A staged from f32 via reg-load+cvt+swizzled ds_write; B via DMA
// (pre-swizzled source, linear dest); reads XOR (ln&7) — R7/R8-proven.
// ---------------------------------------------------------------------------
__global__ __launch_bounds__(128) void qkv_kernel(
    const float* __restrict__ A32,       // [M][512] f32 (= hs)
    const _Float16* __restrict__ WT,     // [768][512]
    const float* __restrict__ pitch,     // [128][64]
    _Float16* __restrict__ qb,           // [B][8][S][64]
    _Float16* __restrict__ kb,           // [B][2][S][64]
    _Float16* __restrict__ vb)           // [B][2][64][S]
{
    const int m0   = blockIdx.x * 64;
    const int n0   = blockIdx.y * 64;
    const int tid  = threadIdx.x;        // 0..127
    const int w    = tid >> 6;           // 0..1
    const int lane = tid & 63;
    const int ln   = lane & 15;
    const int quad = lane >> 4;

    // gs: A0 | A1 | B0 | B1, each 4096 halves (8KB). total 32KB.
    __shared__ __attribute__((aligned(16))) _Float16 gs[16384];

    float4_t acc[2][4];
#pragma unroll
    for (int ms = 0; ms < 2; ++ms)
#pragma unroll
        for (int nt = 0; nt < 4; ++nt) acc[ms][nt] = (float4_t){0.f, 0.f, 0.f, 0.f};

    // B DMA: wave w covers rows [w*32, w*32+32), 4 instrs of 8 rows.
    const int bg = (lane & 7) ^ (lane >> 3);
    const _Float16* Bsrc = WT + (size_t)(n0 + w * 32 + (lane >> 3)) * 512 + bg * 8;
    _Float16* const bwd = gs + 8192 + w * 2048;

#define STAGE_B(buf, k0)                                          \
    do {                                                          \
        GLDS16(Bsrc + (k0),         bwd + (buf) * 4096);          \
        GLDS16(Bsrc + (k0) + 4096,  bwd + (buf) * 4096 + 512);    \
        GLDS16(Bsrc + (k0) + 8192,  bwd + (buf) * 4096 + 1024);   \
        GLDS16(Bsrc + (k0) + 12288, bwd + (buf) * 4096 + 1536);   \
    } while (0)

    // A reg-staging: thread -> row asr (0..63), col-groups acg0..acg0+3.
    const int asr  = tid & 63;
    const int acg0 = (tid >> 6) * 4;
    const int ax   = asr & 7;
    const float* Ar = A32 + (size_t)(m0 + asr) * 512 + acg0 * 8;

    half8_t arr[4];

#define LOAD_A(k0)                                                               \
    do {                                                                         \
        const float* p0 = Ar + (k0);                                             \
        const float* p1 = Ar + (k0) + 8;                                         \
        const float* p2 = Ar + (k0) + 16;                                        \
        const float* p3 = Ar + (k0) + 24;                                        \
        arr[0] = cvt8(*(const float4_t*)p0, *(const float4_t*)(p0 + 4));         \
        arr[1] = cvt8(*(const float4_t*)p1, *(const float4_t*)(p1 + 4));         \
        arr[2] = cvt8(*(const float4_t*)p2, *(const float4_t*)(p2 + 4));         \
        arr[3] = cvt8(*(const float4_t*)p3, *(const float4_t*)(p3 + 4));         \
    } while (0)

#define WRITE_A(buf)                                                             \
    do {                                                                         \
        *(half8_t*)&gs[(buf) * 4096 + asr * 64 + ((acg0 + 0) ^ ax) * 8] = arr[0];\
        *(half8_t*)&gs[(buf) * 4096 + asr * 64 + ((acg0 + 1) ^ ax) * 8] = arr[1];\
        *(half8_t*)&gs[(buf) * 4096 + asr * 64 + ((acg0 + 2) ^ ax) * 8] = arr[2];\
        *(half8_t*)&gs[(buf) * 4096 + asr * 64 + ((acg0 + 3) ^ ax) * 8] = arr[3];\
    } while (0)

    const int colx = (ln & 7) << 3;   // read-side granule XOR (halves)

    // prologue
    STAGE_B(0, 0);
    LOAD_A(0);
    WRITE_A(0);
    asm volatile("s_waitcnt vmcnt(0)" ::: "memory");
    __syncthreads();

#pragma unroll
    for (int kk = 0; kk < 8; ++kk) {
        const int cur = kk & 1;
        if (kk < 7) {
            STAGE_B(cur ^ 1, (kk + 1) * 64);
            LOAD_A((kk + 1) * 64);
        }

#pragma unroll
        for (int ks = 0; ks < 2; ++ks) {
            half8_t af0 = *(const half8_t*)&gs[cur * 4096 +
                (w * 32 + ln) * 64 + ((ks * 32 + quad * 8) ^ colx)];
            half8_t af1 = *(const half8_t*)&gs[cur * 4096 +
                (w * 32 + 16 + ln) * 64 + ((ks * 32 + quad * 8) ^ colx)];
#pragma unroll
            for (int nt = 0; nt < 4; ++nt) {
                half8_t bf = *(const half8_t*)&gs[8192 + cur * 4096 +
                    (nt * 16 + ln) * 64 + ((ks * 32 + quad * 8) ^ colx)];
                acc[0][nt] = __builtin_amdgcn_mfma_f32_16x16x32_f16(af0, bf, acc[0][nt], 0, 0, 0);
                acc[1][nt] = __builtin_amdgcn_mfma_f32_16x16x32_f16(af1, bf, acc[1][nt], 0, 0, 0);
            }
        }

        if (kk < 7) {
            WRITE_A(cur ^ 1);   // buf cur^1 last read in iter kk-1 (barrier'd)
            asm volatile("s_waitcnt vmcnt(0)" ::: "memory");
            __syncthreads();
        }
    }
#undef STAGE_B
#undef LOAD_A
#undef WRITE_A

    // epilogue: region uniform per block; rows w*32 + msub*16 + quad*4 + r
    const int bb  = m0 / S_;
    const int s00 = m0 - bb * S_;

    if (n0 < 512) {
        const int h = n0 >> 6;
#pragma unroll
        for (int ms = 0; ms < 2; ++ms) {
            const int sl_base = w * 32 + ms * 16 + quad * 4;
            const int s_base  = s00 + sl_base;
            const int p_base  = s_base % P_;
#pragma unroll
            for (int r = 0; r < 4; ++r) {
                int p = p_base + r; if (p >= P_) p -= P_;
                const float* pr = pitch + p * 64;
                size_t rowb = ((size_t)(bb * H_ + h) * S_ + s_base + r) * 64;
#pragma unroll
                for (int nt = 0; nt < 4; ++nt) {
                    int dd = nt * 16 + ln;
                    qb[rowb + dd] = (_Float16)((acc[ms][nt][r] + pr[dd]) * QSCALE);
                }
            }
        }
    } else if (n0 < 640) {
        const int h = (n0 - 512) >> 6;
#pragma unroll
        for (int ms = 0; ms < 2; ++ms) {
            const int sl_base = w * 32 + ms * 16 + quad * 4;
            const int s_base  = s00 + sl_base;
            const int p_base  = s_base % P_;
#pragma unroll
            for (int r = 0; r < 4; ++r) {
                int p = p_base + r; if (p >= P_) p -= P_;
                const float* pr = pitch + p * 64;
                size_t rowb = ((size_t)(bb * HKV_ + h) * S_ + s_base + r) * 64;
#pragma unroll
                for (int nt = 0; nt < 4; ++nt) {
                    int dd = nt * 16 + ln;
                    kb[rowb + dd] = (_Float16)(acc[ms][nt][r] + pr[dd]);
                }
            }
        }
    } else {
        // V region: transpose 64s x 64d through gs[0..4095] ([64][64] + XOR),
        // then coalesced 64B row stores (128 threads x 4 half8).
        const int h = (n0 - 640) >> 6;
        __syncthreads();
#pragma unroll
        for (int ms = 0; ms < 2; ++ms) {
            const int sl_base = w * 32 + ms * 16 + quad * 4;
#pragma unroll
            for (int nt = 0; nt < 4; ++nt)
#pragma unroll
                for (int r = 0; r < 4; ++r)
                    gs[(nt * 16 + ln) * 64 + ((sl_base + r) ^ ((ln & 7) << 3))] =
                        (_Float16)acc[ms][nt][r];
        }
        __syncthreads();
        const int rw = tid >> 1;            // d row 0..63
        const int c0 = (tid & 1) * 32;      // s col group
        const int rx = (rw & 7) << 3;
        _Float16* dst = vb + ((size_t)(bb * HKV_ + h) * 64 + rw) * S_ + s00 + c0;
#pragma unroll
        for (int k2 = 0; k2 < 4; ++k2)
            *(half8_t*)(dst + k2 * 8) = *(const half8_t*)&gs[rw * 64 + ((c0 + k2 * 8) ^ rx)];
    }
}

// ---------------------------------------------------------------------------
// Kernel 2: flash attention — Round-2 kernel VERBATIM (best measured:
// 69.8 us, VGPR 40, occ 48, 3 blocks/CU). DO NOT touch (R7 showed the
// epilogue reg-hoist costs an occupancy cliff; R5/R6 alternatives slower).
// ---------------------------------------------------------------------------
__global__ __launch_bounds__(512) void attn_kernel(
    const _Float16* __restrict__ qbuf,  // [B][H][S][64]
    const _Float16* __restrict__ kbuf,  // [B][HKV][S][64]
    const _Float16* __restrict__ vtb,   // [B][HKV][64][S]
    _Float16* __restrict__ ob)          // [B*S][512]
{
    const int qblk = blockIdx.x;
    const int bh   = blockIdx.y;
    const int b    = bh >> 3;
    const int h    = bh & 7;
    const int hkv  = h >> 2;
    const int tid  = threadIdx.x;
    const int w    = tid >> 6;          // 0..7
    const int lane = tid & 63;
    const int ln   = lane & 15;
    const int quad = lane >> 4;

    const _Float16* Q  = qbuf + ((size_t)(b * H_ + h)) * S_ * 64;
    const _Float16* K  = kbuf + ((size_t)(b * HKV_ + hkv)) * S_ * 64;
    const _Float16* Vt = vtb  + ((size_t)(b * HKV_ + hkv)) * 64 * S_;

    __shared__ __attribute__((aligned(16))) _Float16 Ks[128][80];   // 20480 B
    __shared__ __attribute__((aligned(16))) _Float16 VT[64][136];   // 17408 B
    __shared__ __attribute__((aligned(16))) _Float16 Ps[8][16][40]; // 10240 B

    const int qbase = qblk * 64 + (w & 3) * 16;
    const int kk0   = (w >> 2) * 32;

    half8_t qfrag[2];
#pragma unroll
    for (int ks = 0; ks < 2; ++ks)
        qfrag[ks] = *(const half8_t*)&Q[(size_t)(qbase + ln) * 64 + ks * 32 + quad * 8];

    float4_t o[4];
#pragma unroll
    for (int nt = 0; nt < 4; ++nt) o[nt] = (float4_t){0.f, 0.f, 0.f, 0.f};
    float lr[4] = {0.f, 0.f, 0.f, 0.f};

    const int j = tid >> 3, s = tid & 7;        // j: 0..63
    const int r0 = ((j & 1) << 4) | ((j >> 5) << 5) | ((j >> 1) & 15);

    half8_t kr0, kr1, vr0, vr1;
    kr0 = *(const half8_t*)&K[(size_t)j * 64 + s * 8];
    kr1 = *(const half8_t*)&K[(size_t)(64 + j) * 64 + s * 8];
    vr0 = *(const half8_t*)&Vt[(size_t)j * S_ + s * 8];
    vr1 = *(const half8_t*)&Vt[(size_t)j * S_ + 64 + s * 8];

    for (int kt = 0; kt < S_; kt += 128) {
        __syncthreads();
        *(half8_t*)&Ks[r0][s * 8]      = kr0;
        *(half8_t*)&Ks[r0 + 64][s * 8] = kr1;
        *(half8_t*)&VT[j][s * 8]       = vr0;
        *(half8_t*)&VT[j][64 + s * 8]  = vr1;
        __syncthreads();

        if (kt + 128 < S_) {
            kr0 = *(const half8_t*)&K[(size_t)(kt + 128 + j) * 64 + s * 8];
            kr1 = *(const half8_t*)&K[(size_t)(kt + 128 + 64 + j) * 64 + s * 8];
            vr0 = *(const half8_t*)&Vt[(size_t)j * S_ + kt + 128 + s * 8];
            vr1 = *(const half8_t*)&Vt[(size_t)j * S_ + kt + 128 + 64 + s * 8];
        }

#pragma unroll
        for (int h2 = 0; h2 < 2; ++h2) {
            const int kb = h2 * 64 + kk0;

            float4_t sf[2];
            __builtin_amdgcn_s_setprio(1);
#pragma unroll
            for (int c = 0; c < 2; ++c) {
                sf[c] = (float4_t){-SOFT_SHIFT, -SOFT_SHIFT, -SOFT_SHIFT, -SOFT_SHIFT};
#pragma unroll
                for (int ks = 0; ks < 2; ++ks) {
                    half8_t kf = *(const half8_t*)&Ks[kb + c * 16 + ln][ks * 32 + quad * 8];
                    sf[c] = __builtin_amdgcn_mfma_f32_16x16x32_f16(qfrag[ks], kf, sf[c], 0, 0, 0);
                }
            }
            __builtin_amdgcn_s_setprio(0);

#pragma unroll
            for (int rr = 0; rr < 4; ++rr) {
                float p0 = EXP2(fminf(sf[0][rr], SOFT_CLAMP2));
                float p1 = EXP2(fminf(sf[1][rr], SOFT_CLAMP2));
                lr[rr] += p0 + p1;
                half2_t w2; w2[0] = (_Float16)p0; w2[1] = (_Float16)p1;
                *(half2_t*)&Ps[w][quad * 4 + rr][2 * ln] = w2;
            }

            half8_t pf = *(const half8_t*)&Ps[w][ln][quad * 8];
            __builtin_amdgcn_s_setprio(1);
#pragma unroll
            for (int nt = 0; nt < 4; ++nt) {
                half8_t vf = *(const half8_t*)&VT[nt * 16 + ln][kb + quad * 8];
                o[nt] = __builtin_amdgcn_mfma_f32_16x16x32_f16(pf, vf, o[nt], 0, 0, 0);
            }
            __builtin_amdgcn_s_setprio(0);
        }
    }

    __syncthreads();
    if (w >= 4) {
        float* od = (float*)&Ks[0][0] + (w - 4) * 1024;
#pragma unroll
        for (int nt = 0; nt < 4; ++nt)
            *(float4_t*)&od[lane * 16 + nt * 4] = o[nt];
        float* ld = (float*)&Ps[0][0][0] + (w - 4) * 256;
#pragma unroll
        for (int rr = 0; rr < 4; ++rr)
            ld[lane * 4 + rr] = lr[rr];
    }
    __syncthreads();
    if (w < 4) {
        const float* os = (const float*)&Ks[0][0] + w * 1024;
        const float* ls = (const float*)&Ps[0][0][0] + w * 256;
#pragma unroll
        for (int rr = 0; rr < 4; ++rr) {
            float l = lr[rr] + ls[lane * 4 + rr];
            l += __shfl_xor(l, 1);
            l += __shfl_xor(l, 2);
            l += __shfl_xor(l, 4);
            l += __shfl_xor(l, 8);
            float inv = 1.0f / l;
            int qg = qbase + quad * 4 + rr;
            size_t base = ((size_t)(b * S_ + qg)) * 512 + h * 64;
#pragma unroll
            for (int nt = 0; nt < 4; ++nt) {
                float vsum = o[nt][rr] + os[lane * 16 + nt * 4 + rr];
                ob[base + nt * 16 + ln] = (_Float16)(vsum * inv);
            }
        }
    }
}

// ---------------------------------------------------------------------------
// Kernel 3: O(f16) @ Wo -> fp32 out. Same 2-wave 32x64-per-wave structure;
// A and B both DMA-staged (R7-proven conventions).
// ---------------------------------------------------------------------------
__global__ __launch_bounds__(128) void proj_out_kernel(
    const _Float16* __restrict__ A,      // [M][512]
    const _Float16* __restrict__ WT,     // [512][512]
    float* __restrict__ outp)            // [M][512]
{
    const int m0   = blockIdx.x * 64;
    const int n0   = blockIdx.y * 64;
    const int tid  = threadIdx.x;        // 0..127
    const int w    = tid >> 6;           // 0..1
    const int lane = tid & 63;
    const int ln   = lane & 15;
    const int quad = lane >> 4;

    __shared__ __attribute__((aligned(16))) _Float16 gs[16384];

    float4_t acc[2][4];
#pragma unroll
    for (int ms = 0; ms < 2; ++ms)
#pragma unroll
        for (int nt = 0; nt < 4; ++nt) acc[ms][nt] = (float4_t){0.f, 0.f, 0.f, 0.f};

    const int sg = (lane & 7) ^ (lane >> 3);
    const _Float16* Asrc = A  + (size_t)(m0 + w * 32 + (lane >> 3)) * 512 + sg * 8;
    const _Float16* Bsrc = WT + (size_t)(n0 + w * 32 + (lane >> 3)) * 512 + sg * 8;
    _Float16* const awd = gs + w * 2048;
    _Float16* const bwd = gs + 8192 + w * 2048;

#define PRJ_STAGE(buf, k0)                                        \
    do {                                                          \
        GLDS16(Asrc + (k0),         awd + (buf) * 4096);          \
        GLDS16(Asrc + (k0) + 4096,  awd + (buf) * 4096 + 512);    \
        GLDS16(Asrc + (k0) + 8192,  awd + (buf) * 4096 + 1024);   \
        GLDS16(Asrc + (k0) + 12288, awd + (buf) * 4096 + 1536);   \
        GLDS16(Bsrc + (k0),         bwd + (buf) * 4096);          \
        GLDS16(Bsrc + (k0) + 4096,  bwd + (buf) * 4096 + 512);    \
        GLDS16(Bsrc + (k0) + 8192,  bwd + (buf) * 4096 + 1024);   \
        GLDS16(Bsrc + (k0) + 12288, bwd + (buf) * 4096 + 1536);   \
    } while (0)

    const int colx = (ln & 7) << 3;

    PRJ_STAGE(0, 0);
    asm volatile("s_waitcnt vmcnt(0)" ::: "memory");
    __syncthreads();

#pragma unroll
    for (int kk = 0; kk < 8; ++kk) {
        const int cur = kk & 1;
        if (kk < 7) PRJ_STAGE(cur ^ 1, (kk + 1) * 64);

#pragma unroll
        for (int ks = 0; ks < 2; ++ks) {
            half8_t af0 = *(const half8_t*)&gs[cur * 4096 +
                (w * 32 + ln) * 64 + ((ks * 32 + quad * 8) ^ colx)];
            half8_t af1 = *(const half8_t*)&gs[cur * 4096 +
                (w * 32 + 16 + ln) * 64 + ((ks * 32 + quad * 8) ^ colx)];
#pragma unroll
            for (int nt = 0; nt < 4; ++nt) {
                half8_t bf = *(const half8_t*)&gs[8192 + cur * 4096 +
                    (nt * 16 + ln) * 64 + ((ks * 32 + quad * 8) ^ colx)];
                acc[0][nt] = __builtin_amdgcn_mfma_f32_16x16x32_f16(af0, bf, acc[0][nt], 0, 0, 0);
                acc[1][nt] = __builtin_amdgcn_mfma_f32_16x16x32_f16(af1, bf, acc[1][nt], 0, 0, 0);
            }
        }

        if (kk < 7) {
            asm volatile("s_waitcnt vmcnt(0)" ::: "memory");
            __syncthreads();
        }
    }
#undef PRJ_STAGE

#pragma unroll
    for (int ms = 0; ms < 2; ++ms) {
#pragma unroll
        for (int nt = 0; nt < 4; ++nt) {
            int n = n0 + nt * 16 + ln;
#pragma unroll
            for (int r = 0; r < 4; ++r) {
                int m = m0 + w * 32 + ms * 16 + quad * 4 + r;
                outp[(size_t)m * 512 + n] = acc[ms][nt][r];
            }
        }
    }
}

// ---------------------------------------------------------------------------
extern "C" void kernel_launch(void* const* d_in, const int* in_sizes, int n_in,
                              void* d_out, int out_size, void* d_ws, size_t ws_size,
                              hipStream_t stream) {
    const float* hs    = (const float*)d_in[0];
    const float* Wq    = (const float*)d_in[1];
    const float* Wk    = (const float*)d_in[2];
    const float* Wv    = (const float*)d_in[3];
    const float* Wo    = (const float*)d_in[4];
    const float* pitch = (const float*)d_in[5];
    float* out = (float*)d_out;

    // ws layout (f16 elements). qkv reads hs f32 directly (no hs16 pass).
    _Float16* o_buf = (_Float16*)d_ws;                           // M*512 = 3,145,728
    _Float16* q_buf = o_buf + (size_t)M_ * 512;                  // 3,145,728
    _Float16* k_buf = q_buf + (size_t)B_ * H_ * S_ * 64;         //   786,432
    _Float16* v_buf = k_buf + (size_t)B_ * HKV_ * S_ * 64;       //   786,432
    _Float16* wcatT = v_buf + (size_t)B_ * HKV_ * S_ * 64;       //   393,216
    _Float16* woT   = wcatT + (size_t)NQKV * 512;                //   262,144

    prep_kernel<<<160, 256, 0, stream>>>(Wq, Wk, Wv, Wo, wcatT, woT);
    qkv_kernel<<<dim3(M_ / 64, NQKV / 64), 128, 0, stream>>>(hs, wcatT, pitch, q_buf, k_buf, v_buf);
    attn_kernel<<<dim3(S_ / 64, B_ * H_), 512, 0, stream>>>(q_buf, k_buf, v_buf, o_buf);
    proj_out_kernel<<<dim3(M_ / 64, 8), 128, 0, stream>>>(o_buf, woT, out);
}

// Round 10
// 155.858 us; speedup vs baseline: 1.0710x; 1.0710x over previous
//
#include <hip/hip_runtime.h>
#include <hip/hip_fp16.h>

#define B_   2
#define T_   256
#define P_   12
#define C_   512
#define H_   8
#define HKV_ 2
#define D_   64
#define S_   (T_ * P_)   // 3072
#define M_   (B_ * S_)   // 6144
#define NQKV 768         // 512 q + 128 k + 128 v

typedef _Float16 half8_t __attribute__((ext_vector_type(8)));
typedef _Float16 half4_t __attribute__((ext_vector_type(4)));
typedef _Float16 half2_t __attribute__((ext_vector_type(2)));
typedef float    float4_t __attribute__((ext_vector_type(4)));

#if __has_builtin(__builtin_amdgcn_exp2f)
#define EXP2(x) __builtin_amdgcn_exp2f(x)
#else
#define EXP2(x) __expf((x) * 0.69314718f)
#endif

#define SOFT_SHIFT 20.0f
#define SOFT_CLAMP2 15.5f
#define QSCALE (0.125f * 1.44269504f)

// ---------------------------------------------------------------------------
// Kernel 0: prep — cast hs to f16; build transposed f16 weights (R4-verbatim;
// the hs16 cast pass is NET-POSITIVE: qkv re-reads A 12x, f16 halves that).
// ---------------------------------------------------------------------------
__global__ __launch_bounds__(256) void prep_kernel(
    const float* __restrict__ hs,
    const float* __restrict__ Wq, const float* __restrict__ Wk,
    const float* __restrict__ Wv, const float* __restrict__ Wo,
    _Float16* __restrict__ hs16,      // [M][512]
    _Float16* __restrict__ wcatT,     // [768][512]
    _Float16* __restrict__ woT)       // [512][512]
{
    const int blk = blockIdx.x;
    const int tid = threadIdx.x;

    if (blk < 160) {
        __shared__ __attribute__((aligned(16))) _Float16 Ts[64][72];
        if (blk < 96) {
            int nt = blk / 8, kt = blk % 8;
            int n0 = nt * 64, k0 = kt * 64;
            const float* src; int srcN, col0;
            if (n0 < 512)      { src = Wq; srcN = 512; col0 = n0; }
            else if (n0 < 640) { src = Wk; srcN = 128; col0 = n0 - 512; }
            else               { src = Wv; srcN = 128; col0 = n0 - 640; }
#pragma unroll
            for (int i = 0; i < 4; ++i) {
                int row = i * 16 + (tid >> 4);
                int cg  = tid & 15;
                float4_t v = *(const float4_t*)(src + (size_t)(k0 + row) * srcN + col0 + cg * 4);
                Ts[cg * 4 + 0][row] = (_Float16)v[0];
                Ts[cg * 4 + 1][row] = (_Float16)v[1];
                Ts[cg * 4 + 2][row] = (_Float16)v[2];
                Ts[cg * 4 + 3][row] = (_Float16)v[3];
            }
            __syncthreads();
#pragma unroll
            for (int i = 0; i < 2; ++i) {
                int seg = i * 256 + tid;
                int row = seg >> 3, s = seg & 7;
                *(half8_t*)(wcatT + (size_t)(n0 + row) * 512 + k0 + s * 8) =
                    *(const half8_t*)&Ts[row][s * 8];
            }
        } else {
            int t = blk - 96;
            int nt = t / 8, kt = t % 8;
            int n0 = nt * 64, k0 = kt * 64;
#pragma unroll
            for (int i = 0; i < 4; ++i) {
                int row = i * 16 + (tid >> 4);
                int cg  = tid & 15;
                float4_t v = *(const float4_t*)(Wo + (size_t)(k0 + row) * 512 + n0 + cg * 4);
                Ts[cg * 4 + 0][row] = (_Float16)v[0];
                Ts[cg * 4 + 1][row] = (_Float16)v[1];
                Ts[cg * 4 + 2][row] = (_Float16)v[2];
                Ts[cg * 4 + 3][row] = (_Float16)v[3];
            }
            __syncthreads();
#pragma unroll
            for (int i = 0; i < 2; ++i) {
                int seg = i * 256 + tid;
                int row = seg >> 3, s = seg & 7;
                *(half8_t*)(woT + (size_t)(n0 + row) * 512 + k0 + s * 8) =
                    *(const half8_t*)&Ts[row][s * 8];
            }
        }
    } else {
        // hs cast: 192 blocks x 16 iters x 256 threads x float4
        int base = (blk - 160) * 4096;
#pragma unroll
        for (int i = 0; i < 16; ++i) {
            int f4 = base + i * 256 + tid;
            float4_t v = *(const float4_t*)(hs + (size_t)f4 * 4);
            half4_t hv;
            hv[0] = (_Float16)v[0]; hv[1] = (_Float16)v[1];
            hv[2] = (_Float16)v[2]; hv[3] = (_Float16)v[3];
            *(half4_t*)(hs16 + (size_t)f4 * 4) = hv;
        }
    }
}

// ---------------------------------------------------------------------------
// Kernel 1: fused QKV GEMM (R4-verbatim: best-measured non-attn config).
// hs16(M x 512) @ WcatT^T -> q/k/v. 64x64 tiles, BK=64, register prefetch.
// Epilogue: single div/mod per thread; V-region transposed through LDS.
// ---------------------------------------------------------------------------
__global__ __launch_bounds__(256) void qkv_kernel(
    const _Float16* __restrict__ A,      // [M][512]
    const _Float16* __restrict__ WT,     // [768][512]
    const float* __restrict__ pitch,     // [128][64]
    _Float16* __restrict__ qb,           // [B][8][S][64]
    _Float16* __restrict__ kb,           // [B][2][S][64]
    _Float16* __restrict__ vb)           // [B][2][64][S]
{
    const int m0   = blockIdx.x * 64;
    const int n0   = blockIdx.y * 64;
    const int tid  = threadIdx.x;
    const int wave = tid >> 6;
    const int lane = tid & 63;
    const int ln   = lane & 15;
    const int quad = lane >> 4;

    __shared__ __attribute__((aligned(16))) _Float16 As[64][72];
    __shared__ __attribute__((aligned(16))) _Float16 Bs[64][72];

    float4_t acc[4];
#pragma unroll
    for (int nt = 0; nt < 4; ++nt) acc[nt] = (float4_t){0.f, 0.f, 0.f, 0.f};

    const int srow = tid >> 3;
    const int ss   = tid & 7;

    half8_t ar[2], br[2];
#pragma unroll
    for (int i = 0; i < 2; ++i) {
        int row = i * 32 + srow;
        ar[i] = *(const half8_t*)&A [(size_t)(m0 + row) * 512 + ss * 8];
        br[i] = *(const half8_t*)&WT[(size_t)(n0 + row) * 512 + ss * 8];
    }

    for (int k0 = 0; k0 < 512; k0 += 64) {
        __syncthreads();
#pragma unroll
        for (int i = 0; i < 2; ++i) {
            int row = i * 32 + srow;
            *(half8_t*)&As[row][ss * 8] = ar[i];
            *(half8_t*)&Bs[row][ss * 8] = br[i];
        }
        __syncthreads();

        if (k0 + 64 < 512) {
#pragma unroll
            for (int i = 0; i < 2; ++i) {
                int row = i * 32 + srow;
                ar[i] = *(const half8_t*)&A [(size_t)(m0 + row) * 512 + k0 + 64 + ss * 8];
                br[i] = *(const half8_t*)&WT[(size_t)(n0 + row) * 512 + k0 + 64 + ss * 8];
            }
        }

#pragma unroll
        for (int ks = 0; ks < 2; ++ks) {
            half8_t afrag = *(const half8_t*)&As[wave * 16 + ln][ks * 32 + quad * 8];
#pragma unroll
            for (int nt = 0; nt < 4; ++nt) {
                half8_t bfrag = *(const half8_t*)&Bs[nt * 16 + ln][ks * 32 + quad * 8];
                acc[nt] = __builtin_amdgcn_mfma_f32_16x16x32_f16(afrag, bfrag, acc[nt], 0, 0, 0);
            }
        }
    }

    // epilogue: region uniform per block; single mod, incremental p wrap
    const int bb      = m0 / S_;
    const int s00     = m0 - bb * S_;
    const int sl_base = wave * 16 + quad * 4;
    const int s_base  = s00 + sl_base;
    const int p_base  = s_base % P_;

    if (n0 < 512) {
        const int h = n0 >> 6;
#pragma unroll
        for (int r = 0; r < 4; ++r) {
            int p = p_base + r; if (p >= P_) p -= P_;
            const float* pr = pitch + p * 64;
            size_t rowb = ((size_t)(bb * H_ + h) * S_ + s_base + r) * 64;
#pragma unroll
            for (int nt = 0; nt < 4; ++nt) {
                int dd = nt * 16 + ln;
                float v = (acc[nt][r] + pr[dd]) * QSCALE;
                qb[rowb + dd] = (_Float16)v;
            }
        }
    } else if (n0 < 640) {
        const int h = (n0 - 512) >> 6;
#pragma unroll
        for (int r = 0; r < 4; ++r) {
            int p = p_base + r; if (p >= P_) p -= P_;
            const float* pr = pitch + p * 64;
            size_t rowb = ((size_t)(bb * HKV_ + h) * S_ + s_base + r) * 64;
#pragma unroll
            for (int nt = 0; nt < 4; ++nt) {
                int dd = nt * 16 + ln;
                kb[rowb + dd] = (_Float16)(acc[nt][r] + pr[dd]);
            }
        }
    } else {
        // V region: transpose 64s x 64d through LDS (reuse As), coalesced stores.
        const int h = (n0 - 640) >> 6;
        __syncthreads();
#pragma unroll
        for (int nt = 0; nt < 4; ++nt)
#pragma unroll
            for (int r = 0; r < 4; ++r)
                As[nt * 16 + ln][sl_base + r] = (_Float16)acc[nt][r];
        __syncthreads();
        const int rw = tid >> 2;
        const int c0 = (tid & 3) * 16;
        _Float16* dst = vb + ((size_t)(bb * HKV_ + h) * 64 + rw) * S_ + s00 + c0;
        *(half8_t*)dst       = *(const half8_t*)&As[rw][c0];
        *(half8_t*)(dst + 8) = *(const half8_t*)&As[rw][c0 + 8];
    }
}

// ---------------------------------------------------------------------------
// Kernel 2: flash attention — R2/R8 kernel VERBATIM (best measured:
// 68.7-69.9 us across 3 runs, VGPR 40, occ ~49, 3 blocks/CU). DO NOT TOUCH:
// epilogue reg-hoist costs an occupancy cliff (R7); all structural
// alternatives measured slower (R3/R5/R6).
// ---------------------------------------------------------------------------
__global__ __launch_bounds__(512) void attn_kernel(
    const _Float16* __restrict__ qbuf,  // [B][H][S][64]
    const _Float16* __restrict__ kbuf,  // [B][HKV][S][64]
    const _Float16* __restrict__ vtb,   // [B][HKV][64][S]
    _Float16* __restrict__ ob)          // [B*S][512]
{
    const int qblk = blockIdx.x;
    const int bh   = blockIdx.y;
    const int b    = bh >> 3;
    const int h    = bh & 7;
    const int hkv  = h >> 2;
    const int tid  = threadIdx.x;
    const int w    = tid >> 6;          // 0..7
    const int lane = tid & 63;
    const int ln   = lane & 15;
    const int quad = lane >> 4;

    const _Float16* Q  = qbuf + ((size_t)(b * H_ + h)) * S_ * 64;
    const _Float16* K  = kbuf + ((size_t)(b * HKV_ + hkv)) * S_ * 64;
    const _Float16* Vt = vtb  + ((size_t)(b * HKV_ + hkv)) * 64 * S_;

    __shared__ __attribute__((aligned(16))) _Float16 Ks[128][80];   // 20480 B
    __shared__ __attribute__((aligned(16))) _Float16 VT[64][136];   // 17408 B
    __shared__ __attribute__((aligned(16))) _Float16 Ps[8][16][40]; // 10240 B

    const int qbase = qblk * 64 + (w & 3) * 16;
    const int kk0   = (w >> 2) * 32;

    half8_t qfrag[2];
#pragma unroll
    for (int ks = 0; ks < 2; ++ks)
        qfrag[ks] = *(const half8_t*)&Q[(size_t)(qbase + ln) * 64 + ks * 32 + quad * 8];

    float4_t o[4];
#pragma unroll
    for (int nt = 0; nt < 4; ++nt) o[nt] = (float4_t){0.f, 0.f, 0.f, 0.f};
    float lr[4] = {0.f, 0.f, 0.f, 0.f};

    const int j = tid >> 3, s = tid & 7;        // j: 0..63
    const int r0 = ((j & 1) << 4) | ((j >> 5) << 5) | ((j >> 1) & 15);

    half8_t kr0, kr1, vr0, vr1;
    kr0 = *(const half8_t*)&K[(size_t)j * 64 + s * 8];
    kr1 = *(const half8_t*)&K[(size_t)(64 + j) * 64 + s * 8];
    vr0 = *(const half8_t*)&Vt[(size_t)j * S_ + s * 8];
    vr1 = *(const half8_t*)&Vt[(size_t)j * S_ + 64 + s * 8];

    for (int kt = 0; kt < S_; kt += 128) {
        __syncthreads();
        *(half8_t*)&Ks[r0][s * 8]      = kr0;
        *(half8_t*)&Ks[r0 + 64][s * 8] = kr1;
        *(half8_t*)&VT[j][s * 8]       = vr0;
        *(half8_t*)&VT[j][64 + s * 8]  = vr1;
        __syncthreads();

        if (kt + 128 < S_) {
            kr0 = *(const half8_t*)&K[(size_t)(kt + 128 + j) * 64 + s * 8];
            kr1 = *(const half8_t*)&K[(size_t)(kt + 128 + 64 + j) * 64 + s * 8];
            vr0 = *(const half8_t*)&Vt[(size_t)j * S_ + kt + 128 + s * 8];
            vr1 = *(const half8_t*)&Vt[(size_t)j * S_ + kt + 128 + 64 + s * 8];
        }

#pragma unroll
        for (int h2 = 0; h2 < 2; ++h2) {
            const int kb = h2 * 64 + kk0;

            float4_t sf[2];
            __builtin_amdgcn_s_setprio(1);
#pragma unroll
            for (int c = 0; c < 2; ++c) {
                sf[c] = (float4_t){-SOFT_SHIFT, -SOFT_SHIFT, -SOFT_SHIFT, -SOFT_SHIFT};
#pragma unroll
                for (int ks = 0; ks < 2; ++ks) {
                    half8_t kf = *(const half8_t*)&Ks[kb + c * 16 + ln][ks * 32 + quad * 8];
                    sf[c] = __builtin_amdgcn_mfma_f32_16x16x32_f16(qfrag[ks], kf, sf[c], 0, 0, 0);
                }
            }
            __builtin_amdgcn_s_setprio(0);

#pragma unroll
            for (int rr = 0; rr < 4; ++rr) {
                float p0 = EXP2(fminf(sf[0][rr], SOFT_CLAMP2));
                float p1 = EXP2(fminf(sf[1][rr], SOFT_CLAMP2));
                lr[rr] += p0 + p1;
                half2_t w2; w2[0] = (_Float16)p0; w2[1] = (_Float16)p1;
                *(half2_t*)&Ps[w][quad * 4 + rr][2 * ln] = w2;
            }

            half8_t pf = *(const half8_t*)&Ps[w][ln][quad * 8];
            __builtin_amdgcn_s_setprio(1);
#pragma unroll
            for (int nt = 0; nt < 4; ++nt) {
                half8_t vf = *(const half8_t*)&VT[nt * 16 + ln][kb + quad * 8];
                o[nt] = __builtin_amdgcn_mfma_f32_16x16x32_f16(pf, vf, o[nt], 0, 0, 0);
            }
            __builtin_amdgcn_s_setprio(0);
        }
    }

    __syncthreads();
    if (w >= 4) {
        float* od = (float*)&Ks[0][0] + (w - 4) * 1024;
#pragma unroll
        for (int nt = 0; nt < 4; ++nt)
            *(float4_t*)&od[lane * 16 + nt * 4] = o[nt];
        float* ld = (float*)&Ps[0][0][0] + (w - 4) * 256;
#pragma unroll
        for (int rr = 0; rr < 4; ++rr)
            ld[lane * 4 + rr] = lr[rr];
    }
    __syncthreads();
    if (w < 4) {
        const float* os = (const float*)&Ks[0][0] + w * 1024;
        const float* ls = (const float*)&Ps[0][0][0] + w * 256;
#pragma unroll
        for (int rr = 0; rr < 4; ++rr) {
            float l = lr[rr] + ls[lane * 4 + rr];
            l += __shfl_xor(l, 1);
            l += __shfl_xor(l, 2);
            l += __shfl_xor(l, 4);
            l += __shfl_xor(l, 8);
            float inv = 1.0f / l;
            int qg = qbase + quad * 4 + rr;
            size_t base = ((size_t)(b * S_ + qg)) * 512 + h * 64;
#pragma unroll
            for (int nt = 0; nt < 4; ++nt) {
                float vsum = o[nt][rr] + os[lane * 16 + nt * 4 + rr];
                ob[base + nt * 16 + ln] = (_Float16)(vsum * inv);
            }
        }
    }
}

// ---------------------------------------------------------------------------
// Kernel 3: O(f16, M x 512) @ Wo -> fp32 out (R4-verbatim reg-prefetch).
// ---------------------------------------------------------------------------
__global__ __launch_bounds__(256) void proj_out_kernel(
    const _Float16* __restrict__ A,      // [M][512]
    const _Float16* __restrict__ WT,     // [512][512]
    float* __restrict__ outp)            // [M][512]
{
    const int m0   = blockIdx.x * 64;
    const int n0   = blockIdx.y * 64;
    const int tid  = threadIdx.x;
    const int wave = tid >> 6;
    const int lane = tid & 63;
    const int ln   = lane & 15;
    const int quad = lane >> 4;

    __shared__ __attribute__((aligned(16))) _Float16 As[64][72];
    __shared__ __attribute__((aligned(16))) _Float16 Bs[64][72];

    float4_t acc[4];
#pragma unroll
    for (int nt = 0; nt < 4; ++nt) acc[nt] = (float4_t){0.f, 0.f, 0.f, 0.f};

    const int srow = tid >> 3;
    const int ss   = tid & 7;

    half8_t ar[2], br[2];
#pragma unroll
    for (int i = 0; i < 2; ++i) {
        int row = i * 32 + srow;
        ar[i] = *(const half8_t*)&A [(size_t)(m0 + row) * 512 + ss * 8];
        br[i] = *(const half8_t*)&WT[(size_t)(n0 + row) * 512 + ss * 8];
    }

    for (int k0 = 0; k0 < 512; k0 += 64) {
        __syncthreads();
#pragma unroll
        for (int i = 0; i < 2; ++i) {
            int row = i * 32 + srow;
            *(half8_t*)&As[row][ss * 8] = ar[i];
            *(half8_t*)&Bs[row][ss * 8] = br[i];
        }
        __syncthreads();

        if (k0 + 64 < 512) {
#pragma unroll
            for (int i = 0; i < 2; ++i) {
                int row = i * 32 + srow;
                ar[i] = *(const half8_t*)&A [(size_t)(m0 + row) * 512 + k0 + 64 + ss * 8];
                br[i] = *(const half8_t*)&WT[(size_t)(n0 + row) * 512 + k0 + 64 + ss * 8];
            }
        }

#pragma unroll
        for (int ks = 0; ks < 2; ++ks) {
            half8_t afrag = *(const half8_t*)&As[wave * 16 + ln][ks * 32 + quad * 8];
#pragma unroll
            for (int nt = 0; nt < 4; ++nt) {
                half8_t bfrag = *(const half8_t*)&Bs[nt * 16 + ln][ks * 32 + quad * 8];
                acc[nt] = __builtin_amdgcn_mfma_f32_16x16x32_f16(afrag, bfrag, acc[nt], 0, 0, 0);
            }
        }
    }

#pragma unroll
    for (int nt = 0; nt < 4; ++nt) {
        int n = n0 + nt * 16 + ln;
#pragma unroll
        for (int r = 0; r < 4; ++r) {
            int m = m0 + wave * 16 + quad * 4 + r;
            outp[(size_t)m * 512 + n] = acc[nt][r];
        }
    }
}

// ---------------------------------------------------------------------------
extern "C" void kernel_launch(void* const* d_in, const int* in_sizes, int n_in,
                              void* d_out, int out_size, void* d_ws, size_t ws_size,
                              hipStream_t stream) {
    const float* hs    = (const float*)d_in[0];
    const float* Wq    = (const float*)d_in[1];
    const float* Wk    = (const float*)d_in[2];
    const float* Wv    = (const float*)d_in[3];
    const float* Wo    = (const float*)d_in[4];
    const float* pitch = (const float*)d_in[5];
    float* out = (float*)d_out;

    // ws layout (f16 elements). o_buf aliases hs16 (hs16 dead after qkv_kernel).
    _Float16* hs16  = (_Float16*)d_ws;                           // M*512 = 3,145,728
    _Float16* o_buf = hs16;                                      // alias
    _Float16* q_buf = hs16 + (size_t)M_ * 512;                   // 3,145,728
    _Float16* k_buf = q_buf + (size_t)B_ * H_ * S_ * 64;         //   786,432
    _Float16* v_buf = k_buf + (size_t)B_ * HKV_ * S_ * 64;       //   786,432
    _Float16* wcatT = v_buf + (size_t)B_ * HKV_ * S_ * 64;       //   393,216
    _Float16* woT   = wcatT + (size_t)NQKV * 512;                //   262,144

    prep_kernel<<<352, 256, 0, stream>>>(hs, Wq, Wk, Wv, Wo, hs16, wcatT, woT);
    qkv_kernel<<<dim3(M_ / 64, NQKV / 64), 256, 0, stream>>>(hs16, wcatT, pitch, q_buf, k_buf, v_buf);
    attn_kernel<<<dim3(S_ / 64, B_ * H_), 512, 0, stream>>>(q_buf, k_buf, v_buf, o_buf);
    proj_out_kernel<<<dim3(M_ / 64, 8), 256, 0, stream>>>(o_buf, woT, out);
}